// Round 10
// baseline (2630.118 us; speedup 1.0000x reference)
//
#include <hip/hip_runtime.h>

// FPS: input [8, 65536, 3] f32 -> (idx [8,1024] as f32 values, sampled [8,1024,3] f32)
// concatenated flat in d_out.
//
// R10 = R9 protocol (proven: wave0-only sc0/L2 polling + IF fallback, wave15
// IF-mirror) with (a) DPP-based reductions (VALU pipe, ~8cyc/level vs ~40 for
// ds_bpermute shuffles; dist>=0 so fp32 max == unsigned max on bit patterns)
// and (b) NO per-round barriers: barrier1 -> LDS monotone arrival counter
// (16th arriver runs stage2+publish immediately), barrier2 -> round-tagged
// LDS flag (wave0 release-stores t+1 after bc[]; others acquire-spin locally,
// LDS-only traffic — unlike the failed global-poll broadcasts of R4/R8).
//
// 8 WGs/batch (CONTIGUOUS blocks 8b..8b+7 -> same XCD, R6-verified),
// 1024 thr/WG, 8 points/thread in registers. Ties everywhere resolve to the
// smallest global index (numpy argmax first-occurrence); distances are
// uncontracted fp32 in reference order -> bit-exact vs the JAX/numpy ref.
//
// Slot reuse at t+2 ordering (no barriers needed): WG w publishes slot(t)
// only after its 16th arrival => all its waves read bc(t-1) => its wave0 set
// flag(t-1) => wave0 finished polling ALL slots(t-1) => every WG published
// (t-1) => their waves read bc(t-2) => their wave0s finished reading slot(t-2).
// Wave15 reads red[] right after the arrival target; earliest next-round
// red[] overwrite is >= poll-detect + dist-update + stage1 later (~1000cyc
// margin). IF-mirror payload is only consumed by timed-out (cross-XCD)
// pollers; normal path never reads it.

#define NB    8
#define NPTS  65536
#define NSAMP 1024
#define WPB   8      // workgroups per batch
#define TPB   1024   // threads per workgroup
#define PPT   8      // points per thread (WPB*TPB*PPT == NPTS)
#define RECQ  16     // 16 ull = 128 B per record line

typedef unsigned long long ull;

#define DPP(x, ctrl) \
  ((unsigned)__builtin_amdgcn_update_dpp((int)(x), (int)(x), (ctrl), 0xf, 0xf, false))

// max over 64 lanes -> uniform (via lane63); row_shr:N=0x110|N, bcast15/31=0x142/3
__device__ __forceinline__ unsigned umax_wave64(unsigned x) {
  unsigned t;
  t = DPP(x, 0x111); x = t > x ? t : x;
  t = DPP(x, 0x112); x = t > x ? t : x;
  t = DPP(x, 0x114); x = t > x ? t : x;
  t = DPP(x, 0x118); x = t > x ? t : x;
  t = DPP(x, 0x142); x = t > x ? t : x;   // bcast15: row r lane15 -> row r+1
  t = DPP(x, 0x143); x = t > x ? t : x;   // bcast31: lane31 -> rows 2,3
  return (unsigned)__builtin_amdgcn_readlane((int)x, 63);
}
// max over lanes 0..15 of a row -> uniform (via lane15)
__device__ __forceinline__ unsigned umax_row16(unsigned x) {
  unsigned t;
  t = DPP(x, 0x111); x = t > x ? t : x;
  t = DPP(x, 0x112); x = t > x ? t : x;
  t = DPP(x, 0x114); x = t > x ? t : x;
  t = DPP(x, 0x118); x = t > x ? t : x;
  return (unsigned)__builtin_amdgcn_readlane((int)x, 15);
}
// max over lanes 0..7 -> uniform (via lane7); row_shr only pulls lower lanes
__device__ __forceinline__ unsigned umax_low8(unsigned x) {
  unsigned t;
  t = DPP(x, 0x111); x = t > x ? t : x;
  t = DPP(x, 0x112); x = t > x ? t : x;
  t = DPP(x, 0x114); x = t > x ? t : x;
  return (unsigned)__builtin_amdgcn_readlane((int)x, 7);
}

// 3x 8B loads from one 128B line, L1-bypass (sc0) -> reads the XCD L2.
__device__ __forceinline__ void ld3_sc0(const ull* p, ull& a, ull& b, ull& c) {
  asm volatile(
      "global_load_dwordx2 %0, %3, off sc0\n\t"
      "global_load_dwordx2 %1, %3, off offset:8 sc0\n\t"
      "global_load_dwordx2 %2, %3, off offset:16 sc0\n\t"
      "s_waitcnt vmcnt(0)"
      : "=&v"(a), "=&v"(b), "=&v"(c) : "v"(p) : "memory");
}
// 3x 8B stores, fire-and-forget (write-through to XCD L2).
__device__ __forceinline__ void st3_sc0(ull* p, ull a, ull b, ull c) {
  asm volatile(
      "global_store_dwordx2 %3, %0, off sc0\n\t"
      "global_store_dwordx2 %3, %1, off offset:8 sc0\n\t"
      "global_store_dwordx2 %3, %2, off offset:16 sc0"
      :: "v"(a), "v"(b), "v"(c), "v"(p) : "memory");
}

// stage2: select WG winner from red[16][5]; returns packed words + ewin lane
__device__ __forceinline__ void stage2_pack(const unsigned red[16][5], int lane,
                                            ull tag, ull& w0, ull& w1, ull& w2,
                                            int& ewin) {
  const int e = lane & 15;
  const unsigned d2 = red[e][0];
  const unsigned nn = red[e][1];
  const unsigned mx = umax_row16(d2);
  const ull bb = __ballot(d2 == mx) & 0xFFFFull;
  if (__popcll(bb) == 1) {
    ewin = __ffsll(bb) - 1;
  } else {
    const unsigned v = (d2 == mx) ? (65535u - nn) : 0u;   // max -> smallest n
    const unsigned mv = umax_row16(v);
    const ull b2 = __ballot((d2 == mx) && (v == mv)) & 0xFFFFull;
    ewin = __ffsll(b2) - 1;
  }
  const ull k2 = ((ull)d2 << 16) | (ull)(65535u - nn);
  const unsigned xb = red[e][2], yb = red[e][3], zb = red[e][4];
  w0 = (k2 << 16) | tag;
  w1 = ((ull)xb << 32) | ((ull)(yb >> 16) << 16) | tag;
  w2 = ((ull)(yb & 0xFFFFu) << 48) | ((ull)zb << 16) | tag;
}

__global__ __launch_bounds__(TPB, 4)
void fps_kernel(const float* __restrict__ pts, float* __restrict__ out,
                ull* __restrict__ ws) {
  const int wg   = blockIdx.x;   // 0..63
  const int b    = wg >> 3;      // batch: CONTIGUOUS blocks 8b..8b+7 (one XCD)
  const int w    = wg & 7;       // wg within batch, 0..7
  const int tid  = threadIdx.x;
  const int lane = tid & 63;
  const int wave = tid >> 6;     // 0..15

  const float* p = pts + (size_t)b * NPTS * 3;

  float px[PPT], py[PPT], pz[PPT], md[PPT];
#pragma unroll
  for (int i = 0; i < PPT; ++i) {
    const int n = w * (TPB * PPT) + i * TPB + tid;
    px[i] = p[3 * n + 0];
    py[i] = p[3 * n + 1];
    pz[i] = p[3 * n + 2];
    md[i] = 1e10f;               // BIG, matches reference init
  }

  float cx = p[0], cy = p[1], cz = p[2];   // first pick is index 0

  // ws (ull): [0..2048) copy L (sc0/L2): batch b at b*256, 2 par x 8 wg x 16
  //           [2048..4096) copy I (agent/IF): same layout
  ull* baseL = ws + (size_t)b * (2 * WPB * RECQ);
  ull* baseI = ws + (size_t)NB * (2 * WPB * RECQ) + (size_t)b * (2 * WPB * RECQ);

  float* out_idx = out + (size_t)b * NSAMP;
  float* out_smp = out + (size_t)NB * NSAMP + (size_t)b * NSAMP * 3;

  if (w == 0 && tid == 0) {
    out_idx[0] = 0.0f;
    out_smp[0] = cx; out_smp[1] = cy; out_smp[2] = cz;
  }

  __shared__ unsigned red[16][5];  // per-wave {dist_bits, n, x, y, z}
  __shared__ float bc[3];          // winner xyz broadcast
  __shared__ int cnt;              // monotone arrival counter (16 per round)
  __shared__ int flag;             // round-tagged completion flag

  if (tid == 0) { cnt = 0; flag = 0; }
  __syncthreads();                 // one-time init ordering (outside the loop)

  bool useIF = false;              // per-lane permanent fallback to IF polling

  for (int t = 0; t < NSAMP - 1; ++t) {
    // ---- local distance update + thread-local best ----
    float bv = -1.0f; int bi = 0; float bx = 0.f, by = 0.f, bz = 0.f;
#pragma unroll
    for (int i = 0; i < PPT; ++i) {
      const float dx = __fsub_rn(px[i], cx);
      const float dy = __fsub_rn(py[i], cy);
      const float dz = __fsub_rn(pz[i], cz);
      const float d  = __fadd_rn(__fadd_rn(__fmul_rn(dx, dx), __fmul_rn(dy, dy)),
                                 __fmul_rn(dz, dz));
      const float m = fminf(md[i], d);
      md[i] = m;
      if (m > bv) {  // strict > keeps earliest i (smallest n) on ties
        bv = m; bi = i;
        bx = px[i]; by = py[i]; bz = pz[i];
      }
    }

    // ---- stage1: DPP wave64 max + ballot argmax ----
    const unsigned dbits = __float_as_uint(bv);   // bv>=0: bits order as uint
    const unsigned mw = umax_wave64(dbits);
    const bool tied = (dbits == mw);
    const ull bal0 = __ballot(tied);
    int wlane;
    if (__popcll(bal0) == 1) {
      wlane = __ffsll(bal0) - 1;
    } else {
      // exact first-occurrence: smallest (bi, lane) among tied lanes
      ull sel = 0;
#pragma unroll
      for (int ii = 0; ii < PPT; ++ii) {
        const ull bb = __ballot(tied && (bi == ii));
        const bool take = (sel == 0) && (bb != 0);
        sel = take ? bb : sel;
      }
      wlane = __ffsll(sel) - 1;
    }
    if (lane == wlane) {
      red[wave][0] = dbits;
      red[wave][1] = (unsigned)(w * (TPB * PPT) + bi * TPB + tid);
      red[wave][2] = __float_as_uint(bx);
      red[wave][3] = __float_as_uint(by);
      red[wave][4] = __float_as_uint(bz);
    }

    const ull tag = (ull)(unsigned)(t + 1);   // 1..1023; 0xAAAA poison never matches
    const int par = t & 1;

    // ---- arrival: lane0 bumps the monotone counter; 16th arriver publishes ----
    int ret = 0;
    if (lane == 0)
      ret = __hip_atomic_fetch_add(&cnt, 1, __ATOMIC_ACQ_REL,
                                   __HIP_MEMORY_SCOPE_WORKGROUP);
    const int isLast = __shfl((int)(ret == 16 * t + 15), 0, 64);
    if (isLast) {
      ull w0, w1, w2; int ewin;
      stage2_pack(red, lane, tag, w0, w1, w2, ewin);
      if (lane == ewin)
        st3_sc0(baseL + (size_t)(par * WPB + w) * RECQ, w0, w1, w2);
    }

    if (wave == 0) {
      // ---- lanes 0..7 poll copy L (sc0/L2); 256-spin timeout -> copy I ----
      const size_t roff = (size_t)(par * WPB + (lane & 7)) * RECQ;
      const ull* recL = baseL + roff;
      const ull* recI = baseI + roff;
      const bool mine = (lane < WPB);
      bool done = !mine;
      ull r0 = 0, r1 = 0, r2 = 0;
      int spins = 0;
      for (;;) {
        if (!done) {
          if (!useIF) {
            ld3_sc0(recL, r0, r1, r2);
          } else {
            r0 = __hip_atomic_load(recI + 0, __ATOMIC_RELAXED, __HIP_MEMORY_SCOPE_AGENT);
            r1 = __hip_atomic_load(recI + 1, __ATOMIC_RELAXED, __HIP_MEMORY_SCOPE_AGENT);
            r2 = __hip_atomic_load(recI + 2, __ATOMIC_RELAXED, __HIP_MEMORY_SCOPE_AGENT);
          }
          done = ((r0 & 0xFFFFull) == tag) & ((r1 & 0xFFFFull) == tag) &
                 ((r2 & 0xFFFFull) == tag);
          if (!done && !useIF && ++spins > 256) useIF = true;  // cross-XCD fallback
        }
        if (__all(done)) break;
        if (useIF) __builtin_amdgcn_s_sleep(1);
      }

      // ---- stage3: DPP low8 max + ballot -> winner lane src ----
      const unsigned d3  = (unsigned)(r0 >> 32);                 // dist bits
      const unsigned lnv = (unsigned)((r0 >> 16) & 0xFFFFull);   // 65535-n
      const unsigned m3 = umax_low8(d3);
      const ull b3 = __ballot(d3 == m3) & 0xFFull;
      int src;
      if (__popcll(b3) == 1) {
        src = __ffsll(b3) - 1;
      } else {
        const unsigned v = (d3 == m3) ? lnv : 0u;                // max -> smallest n
        const unsigned mv = umax_low8(v);
        const ull b4 = __ballot((d3 == m3) && (v == mv)) & 0xFFull;
        src = __ffsll(b4) - 1;
      }
      const float xx = __uint_as_float((unsigned)(r1 >> 32));
      const float yy = __uint_as_float(((unsigned)((r1 >> 16) & 0xFFFFull) << 16) |
                                       (unsigned)(r2 >> 48));
      const float zz = __uint_as_float((unsigned)((r2 >> 16) & 0xFFFFFFFFull));
      const int n2   = 65535 - (int)__shfl((int)lnv, src, 64);
      const float wx = __shfl(xx, src, 64);
      const float wy = __shfl(yy, src, 64);
      const float wz = __shfl(zz, src, 64);
      if (lane == 0) {
        bc[0] = wx; bc[1] = wy; bc[2] = wz;
        __hip_atomic_store(&flag, t + 1, __ATOMIC_RELEASE,
                           __HIP_MEMORY_SCOPE_WORKGROUP);   // after bc[] writes
        if (w == 0) {
          out_idx[t + 1] = (float)n2;           // exact in fp32
          out_smp[(t + 1) * 3 + 0] = wx;
          out_smp[(t + 1) * 3 + 1] = wy;
          out_smp[(t + 1) * 3 + 2] = wz;
        }
      }
      cx = wx; cy = wy; cz = wz;
    } else {
      if (wave == 15) {
        // ---- IF mirror: wait for all arrivals, duplicate stage2, publish I ----
        while (__hip_atomic_load(&cnt, __ATOMIC_ACQUIRE,
                                 __HIP_MEMORY_SCOPE_WORKGROUP) < 16 * (t + 1)) {}
        ull w0, w1, w2; int ewin;
        stage2_pack(red, lane, tag, w0, w1, w2, ewin);
        if (lane == ewin) {
          ull* recI = baseI + (size_t)(par * WPB + w) * RECQ;
          __hip_atomic_store(recI + 0, w0, __ATOMIC_RELAXED, __HIP_MEMORY_SCOPE_AGENT);
          __hip_atomic_store(recI + 1, w1, __ATOMIC_RELAXED, __HIP_MEMORY_SCOPE_AGENT);
          __hip_atomic_store(recI + 2, w2, __ATOMIC_RELAXED, __HIP_MEMORY_SCOPE_AGENT);
        }
      }
      // ---- local completion wait (LDS flag; no fabric traffic) ----
      while (__hip_atomic_load(&flag, __ATOMIC_ACQUIRE,
                               __HIP_MEMORY_SCOPE_WORKGROUP) < t + 1) {}
      cx = bc[0]; cy = bc[1]; cz = bc[2];
    }
  }
}

extern "C" void kernel_launch(void* const* d_in, const int* in_sizes, int n_in,
                              void* d_out, int out_size, void* d_ws, size_t ws_size,
                              hipStream_t stream) {
  (void)in_sizes; (void)n_in; (void)out_size; (void)ws_size;
  const float* pts = (const float*)d_in[0];
  float* out = (float*)d_out;
  ull* ws = (ull*)d_ws;
  fps_kernel<<<dim3(NB * WPB), dim3(TPB), 0, stream>>>(pts, out, ws);
}

// Round 11
// 2373.678 us; speedup vs baseline: 1.1080x; 1.1080x over previous
//
#include <hip/hip_runtime.h>

// FPS: input [8, 65536, 3] f32 -> (idx [8,1024] as f32 values, sampled [8,1024,3] f32)
// concatenated flat in d_out.
//
// R11 = R9 skeleton (PROVEN: two s_barriers, wave0 lanes0-7 poll sc0/L2 copy
// with IF fallback) + DPP reduces (R10-verified) + store-ack hiding:
//  - wave1 is the publisher (stage2 + sc0 publish + IF mirror). Its store
//    acks drain while wave0 polls/reduces; wave0 carries NO outstanding
//    stores into barrier2, so the compiler's s_waitcnt vmcnt(0) before
//    s_barrier is free on the critical wave.
//  - global output stores moved to wave2 AFTER barrier2 (n2/xyz via LDS):
//    the ack drains under the next round's distance update instead of
//    gating WG0's barrier2 (which gates the whole batch via the polls).
//
// 8 WGs/batch (CONTIGUOUS blocks 8b..8b+7 -> same XCD, R6-verified),
// 1024 thr/WG, 8 points/thread in registers. Ties everywhere resolve to the
// smallest global index (numpy argmax first-occurrence); distances are
// uncontracted fp32 in reference order -> bit-exact vs the JAX/numpy ref.
// Records: 3x 8B self-tagged words (round tag in low16 of each), parity
// double-buffered; stale L2 lines can't fake a future tag; per-word tags
// make mixed-age words harmless. Slot reuse at t+2 ordered by tag
// transitivity through barrier2.

#define NB    8
#define NPTS  65536
#define NSAMP 1024
#define WPB   8      // workgroups per batch
#define TPB   1024   // threads per workgroup
#define PPT   8      // points per thread (WPB*TPB*PPT == NPTS)
#define RECQ  16     // 16 ull = 128 B per record line

typedef unsigned long long ull;

#define DPP(x, ctrl) \
  ((unsigned)__builtin_amdgcn_update_dpp((int)(x), (int)(x), (ctrl), 0xf, 0xf, false))

// max over 64 lanes -> uniform; row_shr:N = 0x110|N, bcast15=0x142, bcast31=0x143
__device__ __forceinline__ unsigned umax_wave64(unsigned x) {
  unsigned t;
  t = DPP(x, 0x111); x = t > x ? t : x;
  t = DPP(x, 0x112); x = t > x ? t : x;
  t = DPP(x, 0x114); x = t > x ? t : x;
  t = DPP(x, 0x118); x = t > x ? t : x;
  t = DPP(x, 0x142); x = t > x ? t : x;   // bcast15: row r lane15 -> row r+1
  t = DPP(x, 0x143); x = t > x ? t : x;   // bcast31: lane31 -> rows 2,3
  return (unsigned)__builtin_amdgcn_readlane((int)x, 63);
}
// max over lanes 0..15 (row 0) -> uniform via lane15
__device__ __forceinline__ unsigned umax_row16(unsigned x) {
  unsigned t;
  t = DPP(x, 0x111); x = t > x ? t : x;
  t = DPP(x, 0x112); x = t > x ? t : x;
  t = DPP(x, 0x114); x = t > x ? t : x;
  t = DPP(x, 0x118); x = t > x ? t : x;
  return (unsigned)__builtin_amdgcn_readlane((int)x, 15);
}
// max over lanes 0..7 -> uniform via lane7
__device__ __forceinline__ unsigned umax_low8(unsigned x) {
  unsigned t;
  t = DPP(x, 0x111); x = t > x ? t : x;
  t = DPP(x, 0x112); x = t > x ? t : x;
  t = DPP(x, 0x114); x = t > x ? t : x;
  return (unsigned)__builtin_amdgcn_readlane((int)x, 7);
}

// 3x 8B loads from one 128B line, L1-bypass (sc0) -> reads the XCD L2.
__device__ __forceinline__ void ld3_sc0(const ull* p, ull& a, ull& b, ull& c) {
  asm volatile(
      "global_load_dwordx2 %0, %3, off sc0\n\t"
      "global_load_dwordx2 %1, %3, off offset:8 sc0\n\t"
      "global_load_dwordx2 %2, %3, off offset:16 sc0\n\t"
      "s_waitcnt vmcnt(0)"
      : "=&v"(a), "=&v"(b), "=&v"(c) : "v"(p) : "memory");
}
// 3x 8B stores, fire-and-forget (write-through to XCD L2).
__device__ __forceinline__ void st3_sc0(ull* p, ull a, ull b, ull c) {
  asm volatile(
      "global_store_dwordx2 %3, %0, off sc0\n\t"
      "global_store_dwordx2 %3, %1, off offset:8 sc0\n\t"
      "global_store_dwordx2 %3, %2, off offset:16 sc0"
      :: "v"(a), "v"(b), "v"(c), "v"(p) : "memory");
}

// stage2: select WG winner from red[16][5]; packed words + winning lane
__device__ __forceinline__ void stage2_pack(const unsigned red[16][5], int lane,
                                            ull tag, ull& w0, ull& w1, ull& w2,
                                            int& ewin) {
  const int e = lane & 15;
  const unsigned d2 = red[e][0];
  const unsigned nn = red[e][1];
  const unsigned mx = umax_row16(d2);
  const ull bb = __ballot(d2 == mx) & 0xFFFFull;
  if (__popcll(bb) == 1) {
    ewin = __ffsll(bb) - 1;
  } else {
    const unsigned v = (d2 == mx) ? (65535u - nn) : 0u;   // max -> smallest n
    const unsigned mv = umax_row16(v);
    const ull b2 = __ballot((d2 == mx) && (v == mv)) & 0xFFFFull;
    ewin = __ffsll(b2) - 1;
  }
  const ull k2 = ((ull)d2 << 16) | (ull)(65535u - nn);
  const unsigned xb = red[e][2], yb = red[e][3], zb = red[e][4];
  w0 = (k2 << 16) | tag;
  w1 = ((ull)xb << 32) | ((ull)(yb >> 16) << 16) | tag;
  w2 = ((ull)(yb & 0xFFFFu) << 48) | ((ull)zb << 16) | tag;
}

__global__ __launch_bounds__(TPB, 4)
void fps_kernel(const float* __restrict__ pts, float* __restrict__ out,
                ull* __restrict__ ws) {
  const int wg   = blockIdx.x;   // 0..63
  const int b    = wg >> 3;      // batch: CONTIGUOUS blocks 8b..8b+7 (one XCD)
  const int w    = wg & 7;       // wg within batch, 0..7
  const int tid  = threadIdx.x;
  const int lane = tid & 63;
  const int wave = tid >> 6;     // 0..15

  const float* p = pts + (size_t)b * NPTS * 3;

  float px[PPT], py[PPT], pz[PPT], md[PPT];
#pragma unroll
  for (int i = 0; i < PPT; ++i) {
    const int n = w * (TPB * PPT) + i * TPB + tid;
    px[i] = p[3 * n + 0];
    py[i] = p[3 * n + 1];
    pz[i] = p[3 * n + 2];
    md[i] = 1e10f;               // BIG, matches reference init
  }

  float cx = p[0], cy = p[1], cz = p[2];   // first pick is index 0

  // ws (ull): [0..2048) copy L (sc0/L2): batch b at b*256, 2 par x 8 wg x 16
  //           [2048..4096) copy I (agent/IF): same layout
  ull* baseL = ws + (size_t)b * (2 * WPB * RECQ);
  ull* baseI = ws + (size_t)NB * (2 * WPB * RECQ) + (size_t)b * (2 * WPB * RECQ);

  float* out_idx = out + (size_t)b * NSAMP;
  float* out_smp = out + (size_t)NB * NSAMP + (size_t)b * NSAMP * 3;

  if (w == 0 && tid == 0) {
    out_idx[0] = 0.0f;
    out_smp[0] = cx; out_smp[1] = cy; out_smp[2] = cz;
  }

  __shared__ unsigned red[16][5];  // per-wave {dist_bits, n, x, y, z}
  __shared__ float bc[3];          // winner xyz
  __shared__ int bn2;              // winner index

  bool useIF = false;              // per-lane permanent fallback to IF polling

  for (int t = 0; t < NSAMP - 1; ++t) {
    // ---- local distance update + thread-local best ----
    float bv = -1.0f; int bi = 0; float bx = 0.f, by = 0.f, bz = 0.f;
#pragma unroll
    for (int i = 0; i < PPT; ++i) {
      const float dx = __fsub_rn(px[i], cx);
      const float dy = __fsub_rn(py[i], cy);
      const float dz = __fsub_rn(pz[i], cz);
      const float d  = __fadd_rn(__fadd_rn(__fmul_rn(dx, dx), __fmul_rn(dy, dy)),
                                 __fmul_rn(dz, dz));
      const float m = fminf(md[i], d);
      md[i] = m;
      if (m > bv) {  // strict > keeps earliest i (smallest n) on ties
        bv = m; bi = i;
        bx = px[i]; by = py[i]; bz = pz[i];
      }
    }

    // ---- stage1: DPP wave64 max + ballot argmax ----
    const unsigned dbits = __float_as_uint(bv);   // bv>=0: bits order as uint
    const unsigned mw = umax_wave64(dbits);
    const bool tied = (dbits == mw);
    const ull bal0 = __ballot(tied);
    int wlane;
    if (__popcll(bal0) == 1) {
      wlane = __ffsll(bal0) - 1;
    } else {
      // exact first-occurrence: smallest (bi, lane) among tied lanes
      ull sel = 0;
#pragma unroll
      for (int ii = 0; ii < PPT; ++ii) {
        const ull bb = __ballot(tied && (bi == ii));
        const bool take = (sel == 0) && (bb != 0);
        sel = take ? bb : sel;
      }
      wlane = __ffsll(sel) - 1;
    }
    if (lane == wlane) {
      red[wave][0] = dbits;
      red[wave][1] = (unsigned)(w * (TPB * PPT) + bi * TPB + tid);
      red[wave][2] = __float_as_uint(bx);
      red[wave][3] = __float_as_uint(by);
      red[wave][4] = __float_as_uint(bz);
    }
    __syncthreads();  // barrier1

    const ull tag = (ull)(unsigned)(t + 1);   // 1..1023; 0xAAAA poison never matches
    const int par = t & 1;

    if (wave == 1) {
      // ---- publisher: stage2, sc0 publish (L2), IF mirror — acks drain
      //      while wave0 polls; wave1 is never the last barrier2 arriver ----
      ull w0, w1, w2; int ewin;
      stage2_pack(red, lane, tag, w0, w1, w2, ewin);
      if (lane == ewin) {
        st3_sc0(baseL + (size_t)(par * WPB + w) * RECQ, w0, w1, w2);
        ull* recI = baseI + (size_t)(par * WPB + w) * RECQ;
        __hip_atomic_store(recI + 0, w0, __ATOMIC_RELAXED, __HIP_MEMORY_SCOPE_AGENT);
        __hip_atomic_store(recI + 1, w1, __ATOMIC_RELAXED, __HIP_MEMORY_SCOPE_AGENT);
        __hip_atomic_store(recI + 2, w2, __ATOMIC_RELAXED, __HIP_MEMORY_SCOPE_AGENT);
      }
    } else if (wave == 0) {
      // ---- lanes 0..7 poll copy L (sc0/L2); 256-spin timeout -> copy I ----
      const size_t roff = (size_t)(par * WPB + (lane & 7)) * RECQ;
      const ull* recL = baseL + roff;
      const ull* recI = baseI + roff;
      const bool mine = (lane < WPB);
      bool done = !mine;
      ull r0 = 0, r1 = 0, r2 = 0;
      int spins = 0;
      for (;;) {
        if (!done) {
          if (!useIF) {
            ld3_sc0(recL, r0, r1, r2);
          } else {
            r0 = __hip_atomic_load(recI + 0, __ATOMIC_RELAXED, __HIP_MEMORY_SCOPE_AGENT);
            r1 = __hip_atomic_load(recI + 1, __ATOMIC_RELAXED, __HIP_MEMORY_SCOPE_AGENT);
            r2 = __hip_atomic_load(recI + 2, __ATOMIC_RELAXED, __HIP_MEMORY_SCOPE_AGENT);
          }
          done = ((r0 & 0xFFFFull) == tag) & ((r1 & 0xFFFFull) == tag) &
                 ((r2 & 0xFFFFull) == tag);
          if (!done && !useIF && ++spins > 256) useIF = true;  // cross-XCD fallback
        }
        if (__all(done)) break;
        if (useIF) __builtin_amdgcn_s_sleep(1);
      }

      // ---- stage3: DPP low8 max + ballot -> winner lane src ----
      const unsigned d3  = (unsigned)(r0 >> 32);                 // dist bits
      const unsigned lnv = (unsigned)((r0 >> 16) & 0xFFFFull);   // 65535-n
      const unsigned m3 = umax_low8(d3);
      const ull b3 = __ballot(d3 == m3) & 0xFFull;
      int src;
      if (__popcll(b3) == 1) {
        src = __ffsll(b3) - 1;
      } else {
        const unsigned v = (d3 == m3) ? lnv : 0u;                // max -> smallest n
        const unsigned mv = umax_low8(v);
        const ull b4 = __ballot((d3 == m3) && (v == mv)) & 0xFFull;
        src = __ffsll(b4) - 1;
      }
      const float xx = __uint_as_float((unsigned)(r1 >> 32));
      const float yy = __uint_as_float(((unsigned)((r1 >> 16) & 0xFFFFull) << 16) |
                                       (unsigned)(r2 >> 48));
      const float zz = __uint_as_float((unsigned)((r2 >> 16) & 0xFFFFFFFFull));
      const int n2   = 65535 - (int)__shfl((int)lnv, src, 64);
      const float wx = __shfl(xx, src, 64);
      const float wy = __shfl(yy, src, 64);
      const float wz = __shfl(zz, src, 64);
      if (lane == 0) {
        bc[0] = wx; bc[1] = wy; bc[2] = wz; bn2 = n2;
      }
    }
    __syncthreads();  // barrier2 (wave0 has no outstanding stores here)

    // ---- deferred output store (off the critical path): ack drains under
    //      the next round's distance update, gated only at barrier1(t+1) ----
    if (w == 0 && wave == 2 && lane == 0) {
      const float wx = bc[0], wy = bc[1], wz = bc[2];
      out_idx[t + 1] = (float)bn2;            // exact in fp32
      out_smp[(t + 1) * 3 + 0] = wx;
      out_smp[(t + 1) * 3 + 1] = wy;
      out_smp[(t + 1) * 3 + 2] = wz;
    }
    cx = bc[0]; cy = bc[1]; cz = bc[2];
  }
}

extern "C" void kernel_launch(void* const* d_in, const int* in_sizes, int n_in,
                              void* d_out, int out_size, void* d_ws, size_t ws_size,
                              hipStream_t stream) {
  (void)in_sizes; (void)n_in; (void)out_size; (void)ws_size;
  const float* pts = (const float*)d_in[0];
  float* out = (float*)d_out;
  ull* ws = (ull*)d_ws;
  fps_kernel<<<dim3(NB * WPB), dim3(TPB), 0, stream>>>(pts, out, ws);
}

// Round 12
// 2291.073 us; speedup vs baseline: 1.1480x; 1.0361x over previous
//
#include <hip/hip_runtime.h>

// FPS: input [8, 65536, 3] f32 -> (idx [8,1024] as f32 values, sampled [8,1024,3] f32)
// concatenated flat in d_out.
//
// R12 = R11 (PROVEN: two barriers; wave1 = publisher (sc0 L2 copy + IF
// mirror), wave0 lanes0-7 poll; wave2 deferred output store; DPP reduces)
// + software-PIPELINED polling: two 3-load sets in flight (A/B ping-pong,
// s_waitcnt vmcnt(3) between tests, data threaded through the wait asm via
// "+v" so the compiler cannot read unlanded regs). Sampling period ~halves,
// cutting the average publish->detect delay. Per-8B-word self-tags make any
// stale/torn sample benign (worst case: one extra iteration). 128-double-
// iter bound -> wave-uniform permanent fallback to agent-scope IF polling
// (placement-independent correctness preserved).
// + micro: red padded to [16][8] (aligned b128 reads), bc as float4 (single
// ds_read_b128 broadcast).
//
// 8 WGs/batch (CONTIGUOUS blocks 8b..8b+7 -> same XCD, R6-verified),
// 1024 thr/WG, 8 points/thread in registers. Ties resolve to the smallest
// global index (numpy argmax first-occurrence); distances are uncontracted
// fp32 in reference order -> bit-exact. Records: 3x 8B self-tagged words
// (round tag in low16 of each), parity double-buffered; stale L2 lines
// can't fake a future tag. Slot reuse at t+2 ordered by tag transitivity
// through barrier2.

#define NB    8
#define NPTS  65536
#define NSAMP 1024
#define WPB   8      // workgroups per batch
#define TPB   1024   // threads per workgroup
#define PPT   8      // points per thread (WPB*TPB*PPT == NPTS)
#define RECQ  16     // 16 ull = 128 B per record line

typedef unsigned long long ull;

#define DPP(x, ctrl) \
  ((unsigned)__builtin_amdgcn_update_dpp((int)(x), (int)(x), (ctrl), 0xf, 0xf, false))

// max over 64 lanes -> uniform; row_shr:N = 0x110|N, bcast15=0x142, bcast31=0x143
__device__ __forceinline__ unsigned umax_wave64(unsigned x) {
  unsigned t;
  t = DPP(x, 0x111); x = t > x ? t : x;
  t = DPP(x, 0x112); x = t > x ? t : x;
  t = DPP(x, 0x114); x = t > x ? t : x;
  t = DPP(x, 0x118); x = t > x ? t : x;
  t = DPP(x, 0x142); x = t > x ? t : x;   // bcast15: row r lane15 -> row r+1
  t = DPP(x, 0x143); x = t > x ? t : x;   // bcast31: lane31 -> rows 2,3
  return (unsigned)__builtin_amdgcn_readlane((int)x, 63);
}
// max over lanes 0..15 (row 0) -> uniform via lane15
__device__ __forceinline__ unsigned umax_row16(unsigned x) {
  unsigned t;
  t = DPP(x, 0x111); x = t > x ? t : x;
  t = DPP(x, 0x112); x = t > x ? t : x;
  t = DPP(x, 0x114); x = t > x ? t : x;
  t = DPP(x, 0x118); x = t > x ? t : x;
  return (unsigned)__builtin_amdgcn_readlane((int)x, 15);
}
// max over lanes 0..7 -> uniform via lane7
__device__ __forceinline__ unsigned umax_low8(unsigned x) {
  unsigned t;
  t = DPP(x, 0x111); x = t > x ? t : x;
  t = DPP(x, 0x112); x = t > x ? t : x;
  t = DPP(x, 0x114); x = t > x ? t : x;
  return (unsigned)__builtin_amdgcn_readlane((int)x, 7);
}

// 3x 8B loads, NO waitcnt (pipelined polling: caller manages vmcnt).
__device__ __forceinline__ void ld3_issue(const ull* p, ull& a, ull& b, ull& c) {
  asm volatile(
      "global_load_dwordx2 %0, %3, off sc0\n\t"
      "global_load_dwordx2 %1, %3, off offset:8 sc0\n\t"
      "global_load_dwordx2 %2, %3, off offset:16 sc0"
      : "=&v"(a), "=&v"(b), "=&v"(c) : "v"(p) : "memory");
}
// wait until <=3 loads outstanding; threads the set through "+v" so uses of
// a/b/c are ordered after this wait in SSA.
__device__ __forceinline__ void wait3_touch(ull& a, ull& b, ull& c) {
  asm volatile("s_waitcnt vmcnt(3)" : "+v"(a), "+v"(b), "+v"(c) :: "memory");
}
__device__ __forceinline__ void wait_vm0() {
  asm volatile("s_waitcnt vmcnt(0)" ::: "memory");
}
// 3x 8B stores, fire-and-forget (write-through to XCD L2).
__device__ __forceinline__ void st3_sc0(ull* p, ull a, ull b, ull c) {
  asm volatile(
      "global_store_dwordx2 %3, %0, off sc0\n\t"
      "global_store_dwordx2 %3, %1, off offset:8 sc0\n\t"
      "global_store_dwordx2 %3, %2, off offset:16 sc0"
      :: "v"(a), "v"(b), "v"(c), "v"(p) : "memory");
}

// stage2: select WG winner from red[16][8]; packed words + winning lane
__device__ __forceinline__ void stage2_pack(const unsigned (*red)[8], int lane,
                                            ull tag, ull& w0, ull& w1, ull& w2,
                                            int& ewin) {
  const int e = lane & 15;
  const unsigned d2 = red[e][0];
  const unsigned nn = red[e][1];
  const unsigned mx = umax_row16(d2);
  const ull bb = __ballot(d2 == mx) & 0xFFFFull;
  if (__popcll(bb) == 1) {
    ewin = __ffsll(bb) - 1;
  } else {
    const unsigned v = (d2 == mx) ? (65535u - nn) : 0u;   // max -> smallest n
    const unsigned mv = umax_row16(v);
    const ull b2 = __ballot((d2 == mx) && (v == mv)) & 0xFFFFull;
    ewin = __ffsll(b2) - 1;
  }
  const ull k2 = ((ull)d2 << 16) | (ull)(65535u - nn);
  const unsigned xb = red[e][2], yb = red[e][3], zb = red[e][4];
  w0 = (k2 << 16) | tag;
  w1 = ((ull)xb << 32) | ((ull)(yb >> 16) << 16) | tag;
  w2 = ((ull)(yb & 0xFFFFu) << 48) | ((ull)zb << 16) | tag;
}

__global__ __launch_bounds__(TPB, 4)
void fps_kernel(const float* __restrict__ pts, float* __restrict__ out,
                ull* __restrict__ ws) {
  const int wg   = blockIdx.x;   // 0..63
  const int b    = wg >> 3;      // batch: CONTIGUOUS blocks 8b..8b+7 (one XCD)
  const int w    = wg & 7;       // wg within batch, 0..7
  const int tid  = threadIdx.x;
  const int lane = tid & 63;
  const int wave = tid >> 6;     // 0..15

  const float* p = pts + (size_t)b * NPTS * 3;

  float px[PPT], py[PPT], pz[PPT], md[PPT];
#pragma unroll
  for (int i = 0; i < PPT; ++i) {
    const int n = w * (TPB * PPT) + i * TPB + tid;
    px[i] = p[3 * n + 0];
    py[i] = p[3 * n + 1];
    pz[i] = p[3 * n + 2];
    md[i] = 1e10f;               // BIG, matches reference init
  }

  float cx = p[0], cy = p[1], cz = p[2];   // first pick is index 0

  // ws (ull): [0..2048) copy L (sc0/L2): batch b at b*256, 2 par x 8 wg x 16
  //           [2048..4096) copy I (agent/IF): same layout
  ull* baseL = ws + (size_t)b * (2 * WPB * RECQ);
  ull* baseI = ws + (size_t)NB * (2 * WPB * RECQ) + (size_t)b * (2 * WPB * RECQ);

  float* out_idx = out + (size_t)b * NSAMP;
  float* out_smp = out + (size_t)NB * NSAMP + (size_t)b * NSAMP * 3;

  if (w == 0 && tid == 0) {
    out_idx[0] = 0.0f;
    out_smp[0] = cx; out_smp[1] = cy; out_smp[2] = cz;
  }

  __shared__ unsigned red[16][8];  // per-wave {dist_bits, n, x, y, z, pad..}
  __shared__ float4 bc4;           // winner xyz (single b128 broadcast)
  __shared__ int bn2;              // winner index

  bool useIF = false;              // permanent fallback to IF polling

  for (int t = 0; t < NSAMP - 1; ++t) {
    // ---- local distance update + thread-local best ----
    float bv = -1.0f; int bi = 0; float bx = 0.f, by = 0.f, bz = 0.f;
#pragma unroll
    for (int i = 0; i < PPT; ++i) {
      const float dx = __fsub_rn(px[i], cx);
      const float dy = __fsub_rn(py[i], cy);
      const float dz = __fsub_rn(pz[i], cz);
      const float d  = __fadd_rn(__fadd_rn(__fmul_rn(dx, dx), __fmul_rn(dy, dy)),
                                 __fmul_rn(dz, dz));
      const float m = fminf(md[i], d);
      md[i] = m;
      if (m > bv) {  // strict > keeps earliest i (smallest n) on ties
        bv = m; bi = i;
        bx = px[i]; by = py[i]; bz = pz[i];
      }
    }

    // ---- stage1: DPP wave64 max + ballot argmax ----
    const unsigned dbits = __float_as_uint(bv);   // bv>=0: bits order as uint
    const unsigned mw = umax_wave64(dbits);
    const bool tied = (dbits == mw);
    const ull bal0 = __ballot(tied);
    int wlane;
    if (__popcll(bal0) == 1) {
      wlane = __ffsll(bal0) - 1;
    } else {
      // exact first-occurrence: smallest (bi, lane) among tied lanes
      ull sel = 0;
#pragma unroll
      for (int ii = 0; ii < PPT; ++ii) {
        const ull bb = __ballot(tied && (bi == ii));
        const bool take = (sel == 0) && (bb != 0);
        sel = take ? bb : sel;
      }
      wlane = __ffsll(sel) - 1;
    }
    if (lane == wlane) {
      red[wave][0] = dbits;
      red[wave][1] = (unsigned)(w * (TPB * PPT) + bi * TPB + tid);
      red[wave][2] = __float_as_uint(bx);
      red[wave][3] = __float_as_uint(by);
      red[wave][4] = __float_as_uint(bz);
    }
    __syncthreads();  // barrier1

    const ull tag = (ull)(unsigned)(t + 1);   // 1..1023; 0xAAAA poison never matches
    const int par = t & 1;

    if (wave == 1) {
      // ---- publisher: stage2, sc0 publish (L2), IF mirror ----
      ull w0, w1, w2; int ewin;
      stage2_pack(red, lane, tag, w0, w1, w2, ewin);
      if (lane == ewin) {
        st3_sc0(baseL + (size_t)(par * WPB + w) * RECQ, w0, w1, w2);
        ull* recI = baseI + (size_t)(par * WPB + w) * RECQ;
        __hip_atomic_store(recI + 0, w0, __ATOMIC_RELAXED, __HIP_MEMORY_SCOPE_AGENT);
        __hip_atomic_store(recI + 1, w1, __ATOMIC_RELAXED, __HIP_MEMORY_SCOPE_AGENT);
        __hip_atomic_store(recI + 2, w2, __ATOMIC_RELAXED, __HIP_MEMORY_SCOPE_AGENT);
      }
    } else if (wave == 0) {
      const size_t roff = (size_t)(par * WPB + (lane & 7)) * RECQ;
      const ull* recL = baseL + roff;
      const ull* recI = baseI + roff;
      const bool mine = (lane < WPB);
      ull r0 = 0, r1 = 0, r2 = 0;
      bool s = !mine;     // per-lane success of the fast path

      if (!useIF) {
        // ---- pipelined sc0/L2 poll: two 3-load sets in flight ----
        if (mine) {
          ull a0, a1, a2, b0, b1, b2;
          bool fromA = true, hit = false;
          ld3_issue(recL, a0, a1, a2);
          for (int it = 0; it < 128; ++it) {
            ld3_issue(recL, b0, b1, b2);
            wait3_touch(a0, a1, a2);          // A landed (B in flight)
            bool m = ((a0 & 0xFFFFull) == tag) & ((a1 & 0xFFFFull) == tag) &
                     ((a2 & 0xFFFFull) == tag);
            if (__all(m)) { hit = true; fromA = true; break; }
            ld3_issue(recL, a0, a1, a2);
            wait3_touch(b0, b1, b2);          // B landed (A in flight)
            m = ((b0 & 0xFFFFull) == tag) & ((b1 & 0xFFFFull) == tag) &
                ((b2 & 0xFFFFull) == tag);
            if (__all(m)) { hit = true; fromA = false; break; }
          }
          wait_vm0();                         // drain strays before reg reuse
          if (hit) {
            if (fromA) { r0 = a0; r1 = a1; r2 = a2; }
            else       { r0 = b0; r1 = b1; r2 = b2; }
            s = true;
          }
        }
      }

      if (!__all(s)) {
        // ---- slow path: agent-scope IF polling (placement-independent) ----
        useIF = true;                          // uniform: all lanes set it
        bool done = !mine;
        for (;;) {
          if (!done) {
            r0 = __hip_atomic_load(recI + 0, __ATOMIC_RELAXED, __HIP_MEMORY_SCOPE_AGENT);
            r1 = __hip_atomic_load(recI + 1, __ATOMIC_RELAXED, __HIP_MEMORY_SCOPE_AGENT);
            r2 = __hip_atomic_load(recI + 2, __ATOMIC_RELAXED, __HIP_MEMORY_SCOPE_AGENT);
            done = ((r0 & 0xFFFFull) == tag) & ((r1 & 0xFFFFull) == tag) &
                   ((r2 & 0xFFFFull) == tag);
          }
          if (__all(done)) break;
          __builtin_amdgcn_s_sleep(1);
        }
      }

      // ---- stage3: DPP low8 max + ballot -> winner lane src ----
      const unsigned d3  = (unsigned)(r0 >> 32);                 // dist bits
      const unsigned lnv = (unsigned)((r0 >> 16) & 0xFFFFull);   // 65535-n
      const unsigned m3 = umax_low8(d3);
      const ull b3 = __ballot(d3 == m3) & 0xFFull;
      int src;
      if (__popcll(b3) == 1) {
        src = __ffsll(b3) - 1;
      } else {
        const unsigned v = (d3 == m3) ? lnv : 0u;                // max -> smallest n
        const unsigned mv = umax_low8(v);
        const ull b4 = __ballot((d3 == m3) && (v == mv)) & 0xFFull;
        src = __ffsll(b4) - 1;
      }
      const float xx = __uint_as_float((unsigned)(r1 >> 32));
      const float yy = __uint_as_float(((unsigned)((r1 >> 16) & 0xFFFFull) << 16) |
                                       (unsigned)(r2 >> 48));
      const float zz = __uint_as_float((unsigned)((r2 >> 16) & 0xFFFFFFFFull));
      const int n2   = 65535 - (int)__shfl((int)lnv, src, 64);
      const float wx = __shfl(xx, src, 64);
      const float wy = __shfl(yy, src, 64);
      const float wz = __shfl(zz, src, 64);
      if (lane == 0) {
        bc4 = make_float4(wx, wy, wz, 0.0f);   // single ds_write_b128
        bn2 = n2;
      }
    }
    __syncthreads();  // barrier2 (wave0 has no outstanding stores here)

    // ---- deferred output store (off the critical path) ----
    const float4 c4 = bc4;                     // single ds_read_b128
    if (w == 0 && wave == 2 && lane == 0) {
      out_idx[t + 1] = (float)bn2;             // exact in fp32
      out_smp[(t + 1) * 3 + 0] = c4.x;
      out_smp[(t + 1) * 3 + 1] = c4.y;
      out_smp[(t + 1) * 3 + 2] = c4.z;
    }
    cx = c4.x; cy = c4.y; cz = c4.z;
  }
}

extern "C" void kernel_launch(void* const* d_in, const int* in_sizes, int n_in,
                              void* d_out, int out_size, void* d_ws, size_t ws_size,
                              hipStream_t stream) {
  (void)in_sizes; (void)n_in; (void)out_size; (void)ws_size;
  const float* pts = (const float*)d_in[0];
  float* out = (float*)d_out;
  ull* ws = (ull*)d_ws;
  fps_kernel<<<dim3(NB * WPB), dim3(TPB), 0, stream>>>(pts, out, ws);
}

// Round 13
// 2157.263 us; speedup vs baseline: 1.2192x; 1.0620x over previous
//
#include <hip/hip_runtime.h>

// FPS: input [8, 65536, 3] f32 -> (idx [8,1024] as f32 values, sampled [8,1024,3] f32)
// concatenated flat in d_out.
//
// R13 = R12 protocol (PROVEN: two barriers; wave1 publisher -> sc0/L2 copy +
// agent-scope IF mirror; wave0 pipelined-polls the L2 copy w/ IF fallback;
// wave2 deferred output store; DPP reduces) with the batch spread over 2x
// more CUs: 16 WGs/batch x 1024 thr x 4 pts/thread (128 blocks).
// Placement: R5(fail)+R6(win) => blocks go to XCDs in CONTIGUOUS chunks of
// total/8; at 128 blocks a 16-WG batch (blocks 16b..16b+15) = one XCD.
// Halves the per-CU issue work (distance update was ~950 cyc of the ~4400
// cyc round); fan-in 8->16 records costs no extra reduce depth (row16 DPP +
// ballot handles 16), only a slightly larger publisher straggler-max.
// Also: red[][5] stride (conflict-free: (e*5)%32 distinct for e<16; R12's
// [16][8] caused 4-way conflicts) and xyz dropped from the hot loop
// (recovered on the single stage1-winner lane via a cndmask tree).
//
// Ties resolve to the smallest global index (numpy argmax first-occurrence);
// distances are uncontracted fp32 in reference order -> bit-exact.
// Records: 3x 8B self-tagged words (round tag in low16 of each), parity
// double-buffered; stale L2 lines can't fake a future tag; per-word tags
// make mixed-age words harmless. Slot reuse at t+2 ordered by tag
// transitivity through barrier2. IF fallback (128-double-iter timeout,
// wave-uniform) keeps correctness independent of block->XCD placement.

#define NB    8
#define NPTS  65536
#define NSAMP 1024
#define WPB   16     // workgroups per batch (one XCD)
#define TPB   1024   // threads per workgroup
#define PPT   4      // points per thread (WPB*TPB*PPT == NPTS)
#define RECQ  16     // 16 ull = 128 B per record line

typedef unsigned long long ull;

#define DPP(x, ctrl) \
  ((unsigned)__builtin_amdgcn_update_dpp((int)(x), (int)(x), (ctrl), 0xf, 0xf, false))

// max over 64 lanes -> uniform; row_shr:N = 0x110|N, bcast15=0x142, bcast31=0x143
__device__ __forceinline__ unsigned umax_wave64(unsigned x) {
  unsigned t;
  t = DPP(x, 0x111); x = t > x ? t : x;
  t = DPP(x, 0x112); x = t > x ? t : x;
  t = DPP(x, 0x114); x = t > x ? t : x;
  t = DPP(x, 0x118); x = t > x ? t : x;
  t = DPP(x, 0x142); x = t > x ? t : x;   // bcast15: row r lane15 -> row r+1
  t = DPP(x, 0x143); x = t > x ? t : x;   // bcast31: lane31 -> rows 2,3
  return (unsigned)__builtin_amdgcn_readlane((int)x, 63);
}
// max over lanes 0..15 (row 0) -> uniform via lane15
__device__ __forceinline__ unsigned umax_row16(unsigned x) {
  unsigned t;
  t = DPP(x, 0x111); x = t > x ? t : x;
  t = DPP(x, 0x112); x = t > x ? t : x;
  t = DPP(x, 0x114); x = t > x ? t : x;
  t = DPP(x, 0x118); x = t > x ? t : x;
  return (unsigned)__builtin_amdgcn_readlane((int)x, 15);
}

// 3x 8B loads, NO waitcnt (pipelined polling: caller manages vmcnt).
__device__ __forceinline__ void ld3_issue(const ull* p, ull& a, ull& b, ull& c) {
  asm volatile(
      "global_load_dwordx2 %0, %3, off sc0\n\t"
      "global_load_dwordx2 %1, %3, off offset:8 sc0\n\t"
      "global_load_dwordx2 %2, %3, off offset:16 sc0"
      : "=&v"(a), "=&v"(b), "=&v"(c) : "v"(p) : "memory");
}
// wait until <=3 loads outstanding; data threaded via "+v" for SSA ordering.
__device__ __forceinline__ void wait3_touch(ull& a, ull& b, ull& c) {
  asm volatile("s_waitcnt vmcnt(3)" : "+v"(a), "+v"(b), "+v"(c) :: "memory");
}
__device__ __forceinline__ void wait_vm0() {
  asm volatile("s_waitcnt vmcnt(0)" ::: "memory");
}
// 3x 8B stores, fire-and-forget (write-through to XCD L2).
__device__ __forceinline__ void st3_sc0(ull* p, ull a, ull b, ull c) {
  asm volatile(
      "global_store_dwordx2 %3, %0, off sc0\n\t"
      "global_store_dwordx2 %3, %1, off offset:8 sc0\n\t"
      "global_store_dwordx2 %3, %2, off offset:16 sc0"
      :: "v"(a), "v"(b), "v"(c), "v"(p) : "memory");
}

// stage2: select WG winner from red[16][5]; packed words + winning lane
__device__ __forceinline__ void stage2_pack(const unsigned (*red)[5], int lane,
                                            ull tag, ull& w0, ull& w1, ull& w2,
                                            int& ewin) {
  const int e = lane & 15;
  const unsigned d2 = red[e][0];
  const unsigned nn = red[e][1];
  const unsigned mx = umax_row16(d2);
  const ull bb = __ballot(d2 == mx) & 0xFFFFull;
  if (__popcll(bb) == 1) {
    ewin = __ffsll(bb) - 1;
  } else {
    const unsigned v = (d2 == mx) ? (65535u - nn) : 0u;   // max -> smallest n
    const unsigned mv = umax_row16(v);
    const ull b2 = __ballot((d2 == mx) && (v == mv)) & 0xFFFFull;
    ewin = __ffsll(b2) - 1;
  }
  const ull k2 = ((ull)d2 << 16) | (ull)(65535u - nn);
  const unsigned xb = red[e][2], yb = red[e][3], zb = red[e][4];
  w0 = (k2 << 16) | tag;
  w1 = ((ull)xb << 32) | ((ull)(yb >> 16) << 16) | tag;
  w2 = ((ull)(yb & 0xFFFFu) << 48) | ((ull)zb << 16) | tag;
}

__global__ __launch_bounds__(TPB, 4)
void fps_kernel(const float* __restrict__ pts, float* __restrict__ out,
                ull* __restrict__ ws) {
  const int wg   = blockIdx.x;   // 0..127
  const int b    = wg >> 4;      // batch: CONTIGUOUS blocks 16b..16b+15 (one XCD)
  const int w    = wg & 15;      // wg within batch, 0..15
  const int tid  = threadIdx.x;
  const int lane = tid & 63;
  const int wave = tid >> 6;     // 0..15

  const float* p = pts + (size_t)b * NPTS * 3;

  float px[PPT], py[PPT], pz[PPT], md[PPT];
#pragma unroll
  for (int i = 0; i < PPT; ++i) {
    const int n = w * (TPB * PPT) + i * TPB + tid;
    px[i] = p[3 * n + 0];
    py[i] = p[3 * n + 1];
    pz[i] = p[3 * n + 2];
    md[i] = 1e10f;               // BIG, matches reference init
  }

  float cx = p[0], cy = p[1], cz = p[2];   // first pick is index 0

  // ws (ull): [0..4096)    copy L (sc0/L2): batch b at b*512, 2 par x 16 wg x 16
  //           [4096..8192) copy I (agent/IF): same layout. 64 KiB total.
  ull* baseL = ws + (size_t)b * (2 * WPB * RECQ);
  ull* baseI = ws + (size_t)NB * (2 * WPB * RECQ) + (size_t)b * (2 * WPB * RECQ);

  float* out_idx = out + (size_t)b * NSAMP;
  float* out_smp = out + (size_t)NB * NSAMP + (size_t)b * NSAMP * 3;

  if (w == 0 && tid == 0) {
    out_idx[0] = 0.0f;
    out_smp[0] = cx; out_smp[1] = cy; out_smp[2] = cz;
  }

  __shared__ unsigned red[16][5];  // per-wave {dist_bits, n, x, y, z}; stride 5
                                   // => banks (e*5)%32 all distinct for e<16
  __shared__ float4 bc4;           // winner xyz (single b128 broadcast)
  __shared__ int bn2;              // winner index

  bool useIF = false;              // permanent fallback to IF polling

  for (int t = 0; t < NSAMP - 1; ++t) {
    // ---- local distance update + thread-local best (value+index only) ----
    float bv = -1.0f; int bi = 0;
#pragma unroll
    for (int i = 0; i < PPT; ++i) {
      const float dx = __fsub_rn(px[i], cx);
      const float dy = __fsub_rn(py[i], cy);
      const float dz = __fsub_rn(pz[i], cz);
      const float d  = __fadd_rn(__fadd_rn(__fmul_rn(dx, dx), __fmul_rn(dy, dy)),
                                 __fmul_rn(dz, dz));
      const float m = fminf(md[i], d);
      md[i] = m;
      if (m > bv) { bv = m; bi = i; }  // strict > keeps earliest i on ties
    }

    // ---- stage1: DPP wave64 max + ballot argmax ----
    const unsigned dbits = __float_as_uint(bv);   // bv>=0: bits order as uint
    const unsigned mw = umax_wave64(dbits);
    const bool tied = (dbits == mw);
    const ull bal0 = __ballot(tied);
    int wlane;
    if (__popcll(bal0) == 1) {
      wlane = __ffsll(bal0) - 1;
    } else {
      // exact first-occurrence: smallest (bi, lane) among tied lanes
      ull sel = 0;
#pragma unroll
      for (int ii = 0; ii < PPT; ++ii) {
        const ull bb = __ballot(tied && (bi == ii));
        const bool take = (sel == 0) && (bb != 0);
        sel = take ? bb : sel;
      }
      wlane = __ffsll(sel) - 1;
    }
    if (lane == wlane) {
      // recover xyz of point bi via cndmask tree (only this lane pays)
      const bool c1 = (bi & 1), c2 = (bi & 2);
      const float qx = c2 ? (c1 ? px[3] : px[2]) : (c1 ? px[1] : px[0]);
      const float qy = c2 ? (c1 ? py[3] : py[2]) : (c1 ? py[1] : py[0]);
      const float qz = c2 ? (c1 ? pz[3] : pz[2]) : (c1 ? pz[1] : pz[0]);
      red[wave][0] = dbits;
      red[wave][1] = (unsigned)(w * (TPB * PPT) + bi * TPB + tid);
      red[wave][2] = __float_as_uint(qx);
      red[wave][3] = __float_as_uint(qy);
      red[wave][4] = __float_as_uint(qz);
    }
    __syncthreads();  // barrier1

    const ull tag = (ull)(unsigned)(t + 1);   // 1..1023; 0xAAAA poison never matches
    const int par = t & 1;

    if (wave == 1) {
      // ---- publisher: stage2, sc0 publish (L2), IF mirror ----
      ull w0, w1, w2; int ewin;
      stage2_pack(red, lane, tag, w0, w1, w2, ewin);
      if (lane == ewin) {
        st3_sc0(baseL + (size_t)(par * WPB + w) * RECQ, w0, w1, w2);
        ull* recI = baseI + (size_t)(par * WPB + w) * RECQ;
        __hip_atomic_store(recI + 0, w0, __ATOMIC_RELAXED, __HIP_MEMORY_SCOPE_AGENT);
        __hip_atomic_store(recI + 1, w1, __ATOMIC_RELAXED, __HIP_MEMORY_SCOPE_AGENT);
        __hip_atomic_store(recI + 2, w2, __ATOMIC_RELAXED, __HIP_MEMORY_SCOPE_AGENT);
      }
    } else if (wave == 0) {
      const size_t roff = (size_t)(par * WPB + (lane & 15)) * RECQ;
      const ull* recL = baseL + roff;
      const ull* recI = baseI + roff;
      const bool mine = (lane < WPB);
      ull r0 = 0, r1 = 0, r2 = 0;
      bool s = !mine;     // per-lane success of the fast path

      if (!useIF) {
        // ---- pipelined sc0/L2 poll: two 3-load sets in flight ----
        if (mine) {
          ull a0, a1, a2, b0, b1, b2;
          bool fromA = true, hit = false;
          ld3_issue(recL, a0, a1, a2);
          for (int it = 0; it < 128; ++it) {
            ld3_issue(recL, b0, b1, b2);
            wait3_touch(a0, a1, a2);          // A landed (B in flight)
            bool m = ((a0 & 0xFFFFull) == tag) & ((a1 & 0xFFFFull) == tag) &
                     ((a2 & 0xFFFFull) == tag);
            if (__all(m)) { hit = true; fromA = true; break; }
            ld3_issue(recL, a0, a1, a2);
            wait3_touch(b0, b1, b2);          // B landed (A in flight)
            m = ((b0 & 0xFFFFull) == tag) & ((b1 & 0xFFFFull) == tag) &
                ((b2 & 0xFFFFull) == tag);
            if (__all(m)) { hit = true; fromA = false; break; }
          }
          wait_vm0();                         // drain strays before reg reuse
          if (hit) {
            if (fromA) { r0 = a0; r1 = a1; r2 = a2; }
            else       { r0 = b0; r1 = b1; r2 = b2; }
            s = true;
          }
        }
      }

      if (!__all(s)) {
        // ---- slow path: agent-scope IF polling (placement-independent) ----
        useIF = true;                          // uniform: all lanes set it
        bool done = !mine;
        for (;;) {
          if (!done) {
            r0 = __hip_atomic_load(recI + 0, __ATOMIC_RELAXED, __HIP_MEMORY_SCOPE_AGENT);
            r1 = __hip_atomic_load(recI + 1, __ATOMIC_RELAXED, __HIP_MEMORY_SCOPE_AGENT);
            r2 = __hip_atomic_load(recI + 2, __ATOMIC_RELAXED, __HIP_MEMORY_SCOPE_AGENT);
            done = ((r0 & 0xFFFFull) == tag) & ((r1 & 0xFFFFull) == tag) &
                   ((r2 & 0xFFFFull) == tag);
          }
          if (__all(done)) break;
          __builtin_amdgcn_s_sleep(1);
        }
      }

      // ---- stage3: DPP row16 max + ballot over 16 records -> winner src ----
      const unsigned d3  = (unsigned)(r0 >> 32);                 // dist bits
      const unsigned lnv = (unsigned)((r0 >> 16) & 0xFFFFull);   // 65535-n
      const unsigned m3 = umax_row16(d3);
      const ull b3 = __ballot(d3 == m3) & 0xFFFFull;
      int src;
      if (__popcll(b3) == 1) {
        src = __ffsll(b3) - 1;
      } else {
        const unsigned v = (d3 == m3) ? lnv : 0u;                // max -> smallest n
        const unsigned mv = umax_row16(v);
        const ull b4 = __ballot((d3 == m3) && (v == mv)) & 0xFFFFull;
        src = __ffsll(b4) - 1;
      }
      const float xx = __uint_as_float((unsigned)(r1 >> 32));
      const float yy = __uint_as_float(((unsigned)((r1 >> 16) & 0xFFFFull) << 16) |
                                       (unsigned)(r2 >> 48));
      const float zz = __uint_as_float((unsigned)((r2 >> 16) & 0xFFFFFFFFull));
      const int n2   = 65535 - (int)__shfl((int)lnv, src, 64);
      const float wx = __shfl(xx, src, 64);
      const float wy = __shfl(yy, src, 64);
      const float wz = __shfl(zz, src, 64);
      if (lane == 0) {
        bc4 = make_float4(wx, wy, wz, 0.0f);   // single ds_write_b128
        bn2 = n2;
      }
    }
    __syncthreads();  // barrier2 (wave0 has no outstanding stores here)

    // ---- deferred output store (off the critical path) ----
    const float4 c4 = bc4;                     // single ds_read_b128
    if (w == 0 && wave == 2 && lane == 0) {
      out_idx[t + 1] = (float)bn2;             // exact in fp32
      out_smp[(t + 1) * 3 + 0] = c4.x;
      out_smp[(t + 1) * 3 + 1] = c4.y;
      out_smp[(t + 1) * 3 + 2] = c4.z;
    }
    cx = c4.x; cy = c4.y; cz = c4.z;
  }
}

extern "C" void kernel_launch(void* const* d_in, const int* in_sizes, int n_in,
                              void* d_out, int out_size, void* d_ws, size_t ws_size,
                              hipStream_t stream) {
  (void)in_sizes; (void)n_in; (void)out_size; (void)ws_size;
  const float* pts = (const float*)d_in[0];
  float* out = (float*)d_out;
  ull* ws = (ull*)d_ws;
  fps_kernel<<<dim3(NB * WPB), dim3(TPB), 0, stream>>>(pts, out, ws);
}

// Round 14
// 2140.230 us; speedup vs baseline: 1.2289x; 1.0080x over previous
//
#include <hip/hip_runtime.h>

// FPS: input [8, 65536, 3] f32 -> (idx [8,1024] as f32 values, sampled [8,1024,3] f32)
// concatenated flat in d_out.
//
// R14 = R13 protocol (PROVEN: two barriers; wave1 publisher -> sc0/L2 copy +
// agent-scope IF mirror; wave0 pipelined-polls w/ IF fallback; deferred
// output store; DPP reduces; conflict-free red[][5]) spread wider + smaller
// WGs: 32 WGs/batch x 512 thr x 4 pts/thread (256 blocks = 1 WG/CU, 8 waves).
//  - per-SIMD issue load halves again (2 waves/SIMD): dist+stage1 ~350->~230
//  - s_barriers over 8 waves, cheaper + less intra-WG straggle
//  - placement: R6-verified contiguous chunking -> 256 blocks = 32/XCD ->
//    batch 32b..32b+31 = one XCD. Fan-in 32 records: lanes 0..31 poll,
//    stage3 = full wave64 DPP reduce (lane i and i+32 duplicate a record;
//    ffs picks the lower lane; value-based n-tie ballots are duplicate-safe).
//
// Ties resolve to the smallest global index (numpy argmax first-occurrence);
// distances are uncontracted fp32 in reference order -> bit-exact.
// Records: 3x 8B self-tagged words (round tag in low16 of each), parity
// double-buffered; stale L2 lines can't fake a future tag; per-word tags
// make mixed-age words harmless. Slot reuse at t+2 ordered by tag
// transitivity through barrier2. IF fallback (wave-uniform, 128-double-iter
// timeout) keeps correctness independent of block->XCD placement.

#define NB    8
#define NPTS  65536
#define NSAMP 1024
#define WPB   32     // workgroups per batch (one XCD at 256 blocks)
#define TPB   512    // threads per workgroup (8 waves)
#define NWAVE 8
#define PPT   4      // points per thread (WPB*TPB*PPT == NPTS)
#define RECQ  16     // 16 ull = 128 B per record line

typedef unsigned long long ull;

#define DPP(x, ctrl) \
  ((unsigned)__builtin_amdgcn_update_dpp((int)(x), (int)(x), (ctrl), 0xf, 0xf, false))

// max over 64 lanes -> uniform; row_shr:N = 0x110|N, bcast15=0x142, bcast31=0x143
__device__ __forceinline__ unsigned umax_wave64(unsigned x) {
  unsigned t;
  t = DPP(x, 0x111); x = t > x ? t : x;
  t = DPP(x, 0x112); x = t > x ? t : x;
  t = DPP(x, 0x114); x = t > x ? t : x;
  t = DPP(x, 0x118); x = t > x ? t : x;
  t = DPP(x, 0x142); x = t > x ? t : x;   // bcast15: row r lane15 -> row r+1
  t = DPP(x, 0x143); x = t > x ? t : x;   // bcast31: lane31 -> rows 2,3
  return (unsigned)__builtin_amdgcn_readlane((int)x, 63);
}
// max over lanes 0..7 -> uniform via lane7 (groups of 16 see their row's shr)
__device__ __forceinline__ unsigned umax_low8(unsigned x) {
  unsigned t;
  t = DPP(x, 0x111); x = t > x ? t : x;
  t = DPP(x, 0x112); x = t > x ? t : x;
  t = DPP(x, 0x114); x = t > x ? t : x;
  return (unsigned)__builtin_amdgcn_readlane((int)x, 7);
}

// 3x 8B loads, NO waitcnt (pipelined polling: caller manages vmcnt).
__device__ __forceinline__ void ld3_issue(const ull* p, ull& a, ull& b, ull& c) {
  asm volatile(
      "global_load_dwordx2 %0, %3, off sc0\n\t"
      "global_load_dwordx2 %1, %3, off offset:8 sc0\n\t"
      "global_load_dwordx2 %2, %3, off offset:16 sc0"
      : "=&v"(a), "=&v"(b), "=&v"(c) : "v"(p) : "memory");
}
// wait until <=3 loads outstanding; data threaded via "+v" for SSA ordering.
__device__ __forceinline__ void wait3_touch(ull& a, ull& b, ull& c) {
  asm volatile("s_waitcnt vmcnt(3)" : "+v"(a), "+v"(b), "+v"(c) :: "memory");
}
__device__ __forceinline__ void wait_vm0() {
  asm volatile("s_waitcnt vmcnt(0)" ::: "memory");
}
// 3x 8B stores, fire-and-forget (write-through to XCD L2).
__device__ __forceinline__ void st3_sc0(ull* p, ull a, ull b, ull c) {
  asm volatile(
      "global_store_dwordx2 %3, %0, off sc0\n\t"
      "global_store_dwordx2 %3, %1, off offset:8 sc0\n\t"
      "global_store_dwordx2 %3, %2, off offset:16 sc0"
      :: "v"(a), "v"(b), "v"(c), "v"(p) : "memory");
}

// stage2: select WG winner from red[8][5]; packed words + winning lane
__device__ __forceinline__ void stage2_pack(const unsigned (*red)[5], int lane,
                                            ull tag, ull& w0, ull& w1, ull& w2,
                                            int& ewin) {
  const int e = lane & 7;
  const unsigned d2 = red[e][0];
  const unsigned nn = red[e][1];
  const unsigned mx = umax_low8(d2);
  const ull bb = __ballot(d2 == mx) & 0xFFull;
  if (__popcll(bb) == 1) {
    ewin = __ffsll(bb) - 1;
  } else {
    const unsigned v = (d2 == mx) ? (65535u - nn) : 0u;   // max -> smallest n
    const unsigned mv = umax_low8(v);
    const ull b2 = __ballot((d2 == mx) && (v == mv)) & 0xFFull;
    ewin = __ffsll(b2) - 1;
  }
  const ull k2 = ((ull)d2 << 16) | (ull)(65535u - nn);
  const unsigned xb = red[e][2], yb = red[e][3], zb = red[e][4];
  w0 = (k2 << 16) | tag;
  w1 = ((ull)xb << 32) | ((ull)(yb >> 16) << 16) | tag;
  w2 = ((ull)(yb & 0xFFFFu) << 48) | ((ull)zb << 16) | tag;
}

__global__ __launch_bounds__(TPB, 4)
void fps_kernel(const float* __restrict__ pts, float* __restrict__ out,
                ull* __restrict__ ws) {
  const int wg   = blockIdx.x;   // 0..255
  const int b    = wg >> 5;      // batch: CONTIGUOUS blocks 32b..32b+31 (one XCD)
  const int w    = wg & 31;      // wg within batch, 0..31
  const int tid  = threadIdx.x;
  const int lane = tid & 63;
  const int wave = tid >> 6;     // 0..7

  const float* p = pts + (size_t)b * NPTS * 3;

  float px[PPT], py[PPT], pz[PPT], md[PPT];
#pragma unroll
  for (int i = 0; i < PPT; ++i) {
    const int n = w * (TPB * PPT) + i * TPB + tid;
    px[i] = p[3 * n + 0];
    py[i] = p[3 * n + 1];
    pz[i] = p[3 * n + 2];
    md[i] = 1e10f;               // BIG, matches reference init
  }

  float cx = p[0], cy = p[1], cz = p[2];   // first pick is index 0

  // ws (ull): [0..8192)     copy L (sc0/L2): batch b at b*1024, 2 par x 32 wg x 16
  //           [8192..16384) copy I (agent/IF): same layout. 128 KiB total.
  ull* baseL = ws + (size_t)b * (2 * WPB * RECQ);
  ull* baseI = ws + (size_t)NB * (2 * WPB * RECQ) + (size_t)b * (2 * WPB * RECQ);

  float* out_idx = out + (size_t)b * NSAMP;
  float* out_smp = out + (size_t)NB * NSAMP + (size_t)b * NSAMP * 3;

  if (w == 0 && tid == 0) {
    out_idx[0] = 0.0f;
    out_smp[0] = cx; out_smp[1] = cy; out_smp[2] = cz;
  }

  __shared__ unsigned red[NWAVE][5];  // per-wave {dist_bits, n, x, y, z}; stride 5
                                      // -> banks (e*5)%32 distinct for e<8
  __shared__ float4 bc4;              // winner xyz (single b128 broadcast)
  __shared__ int bn2;                 // winner index

  bool useIF = false;                 // permanent fallback to IF polling

  for (int t = 0; t < NSAMP - 1; ++t) {
    // ---- local distance update + thread-local best (value+index only) ----
    float bv = -1.0f; int bi = 0;
#pragma unroll
    for (int i = 0; i < PPT; ++i) {
      const float dx = __fsub_rn(px[i], cx);
      const float dy = __fsub_rn(py[i], cy);
      const float dz = __fsub_rn(pz[i], cz);
      const float d  = __fadd_rn(__fadd_rn(__fmul_rn(dx, dx), __fmul_rn(dy, dy)),
                                 __fmul_rn(dz, dz));
      const float m = fminf(md[i], d);
      md[i] = m;
      if (m > bv) { bv = m; bi = i; }  // strict > keeps earliest i on ties
    }

    // ---- stage1: DPP wave64 max + ballot argmax ----
    const unsigned dbits = __float_as_uint(bv);   // bv>=0: bits order as uint
    const unsigned mw = umax_wave64(dbits);
    const bool tied = (dbits == mw);
    const ull bal0 = __ballot(tied);
    int wlane;
    if (__popcll(bal0) == 1) {
      wlane = __ffsll(bal0) - 1;
    } else {
      // exact first-occurrence: smallest (bi, lane) among tied lanes
      ull sel = 0;
#pragma unroll
      for (int ii = 0; ii < PPT; ++ii) {
        const ull bb = __ballot(tied && (bi == ii));
        const bool take = (sel == 0) && (bb != 0);
        sel = take ? bb : sel;
      }
      wlane = __ffsll(sel) - 1;
    }
    if (lane == wlane) {
      // recover xyz of point bi via cndmask tree (only this lane pays)
      const bool c1 = (bi & 1), c2 = (bi & 2);
      const float qx = c2 ? (c1 ? px[3] : px[2]) : (c1 ? px[1] : px[0]);
      const float qy = c2 ? (c1 ? py[3] : py[2]) : (c1 ? py[1] : py[0]);
      const float qz = c2 ? (c1 ? pz[3] : pz[2]) : (c1 ? pz[1] : pz[0]);
      red[wave][0] = dbits;
      red[wave][1] = (unsigned)(w * (TPB * PPT) + bi * TPB + tid);
      red[wave][2] = __float_as_uint(qx);
      red[wave][3] = __float_as_uint(qy);
      red[wave][4] = __float_as_uint(qz);
    }
    __syncthreads();  // barrier1 (8 waves)

    const ull tag = (ull)(unsigned)(t + 1);   // 1..1023; 0xAAAA poison never matches
    const int par = t & 1;

    if (wave == 1) {
      // ---- publisher: stage2, sc0 publish (L2), IF mirror ----
      ull w0, w1, w2; int ewin;
      stage2_pack(red, lane, tag, w0, w1, w2, ewin);
      if (lane == ewin) {
        st3_sc0(baseL + (size_t)(par * WPB + w) * RECQ, w0, w1, w2);
        ull* recI = baseI + (size_t)(par * WPB + w) * RECQ;
        __hip_atomic_store(recI + 0, w0, __ATOMIC_RELAXED, __HIP_MEMORY_SCOPE_AGENT);
        __hip_atomic_store(recI + 1, w1, __ATOMIC_RELAXED, __HIP_MEMORY_SCOPE_AGENT);
        __hip_atomic_store(recI + 2, w2, __ATOMIC_RELAXED, __HIP_MEMORY_SCOPE_AGENT);
      }
    } else if (wave == 0) {
      const size_t roff = (size_t)(par * WPB + (lane & 31)) * RECQ;
      const ull* recL = baseL + roff;
      const ull* recI = baseI + roff;
      const bool mine = (lane < WPB);
      ull r0 = 0, r1 = 0, r2 = 0;
      bool s = !mine;     // per-lane success of the fast path

      if (!useIF) {
        // ---- pipelined sc0/L2 poll: two 3-load sets in flight ----
        if (mine) {
          ull a0, a1, a2, b0, b1, b2;
          bool fromA = true, hit = false;
          ld3_issue(recL, a0, a1, a2);
          for (int it = 0; it < 128; ++it) {
            ld3_issue(recL, b0, b1, b2);
            wait3_touch(a0, a1, a2);          // A landed (B in flight)
            bool m = ((a0 & 0xFFFFull) == tag) & ((a1 & 0xFFFFull) == tag) &
                     ((a2 & 0xFFFFull) == tag);
            if (__all(m)) { hit = true; fromA = true; break; }
            ld3_issue(recL, a0, a1, a2);
            wait3_touch(b0, b1, b2);          // B landed (A in flight)
            m = ((b0 & 0xFFFFull) == tag) & ((b1 & 0xFFFFull) == tag) &
                ((b2 & 0xFFFFull) == tag);
            if (__all(m)) { hit = true; fromA = false; break; }
          }
          wait_vm0();                         // drain strays before reg reuse
          if (hit) {
            if (fromA) { r0 = a0; r1 = a1; r2 = a2; }
            else       { r0 = b0; r1 = b1; r2 = b2; }
            s = true;
          }
        }
      }

      if (!__all(s)) {
        // ---- slow path: agent-scope IF polling (placement-independent) ----
        useIF = true;                          // uniform: all lanes set it
        bool done = !mine;
        for (;;) {
          if (!done) {
            r0 = __hip_atomic_load(recI + 0, __ATOMIC_RELAXED, __HIP_MEMORY_SCOPE_AGENT);
            r1 = __hip_atomic_load(recI + 1, __ATOMIC_RELAXED, __HIP_MEMORY_SCOPE_AGENT);
            r2 = __hip_atomic_load(recI + 2, __ATOMIC_RELAXED, __HIP_MEMORY_SCOPE_AGENT);
            done = ((r0 & 0xFFFFull) == tag) & ((r1 & 0xFFFFull) == tag) &
                   ((r2 & 0xFFFFull) == tag);
          }
          if (__all(done)) break;
          __builtin_amdgcn_s_sleep(1);
        }
      }

      // ---- stage3: full wave64 DPP max + ballot over 32 records (lanes
      //      32..63 duplicate 0..31 -> ffs picks the lower; value-based
      //      n-tie ballots are duplicate-safe) ----
      const unsigned d3  = (unsigned)(r0 >> 32);                 // dist bits
      const unsigned lnv = (unsigned)((r0 >> 16) & 0xFFFFull);   // 65535-n
      const unsigned m3 = umax_wave64(d3);
      const ull b3 = __ballot(d3 == m3);
      int src;
      if (__popcll(b3) == 1) {
        src = __ffsll(b3) - 1;
      } else {
        const unsigned v = (d3 == m3) ? lnv : 0u;                // max -> smallest n
        const unsigned mv = umax_wave64(v);
        const ull b4 = __ballot((d3 == m3) && (v == mv));
        src = __ffsll(b4) - 1;
      }
      const float xx = __uint_as_float((unsigned)(r1 >> 32));
      const float yy = __uint_as_float(((unsigned)((r1 >> 16) & 0xFFFFull) << 16) |
                                       (unsigned)(r2 >> 48));
      const float zz = __uint_as_float((unsigned)((r2 >> 16) & 0xFFFFFFFFull));
      const int n2   = 65535 - (int)__shfl((int)lnv, src, 64);
      const float wx = __shfl(xx, src, 64);
      const float wy = __shfl(yy, src, 64);
      const float wz = __shfl(zz, src, 64);
      if (lane == 0) {
        bc4 = make_float4(wx, wy, wz, 0.0f);   // single ds_write_b128
        bn2 = n2;
      }
    }
    __syncthreads();  // barrier2 (wave0 has no outstanding stores here)

    // ---- deferred output store (off the critical path) ----
    const float4 c4 = bc4;                     // single ds_read_b128
    if (w == 0 && wave == 2 && lane == 0) {
      out_idx[t + 1] = (float)bn2;             // exact in fp32
      out_smp[(t + 1) * 3 + 0] = c4.x;
      out_smp[(t + 1) * 3 + 1] = c4.y;
      out_smp[(t + 1) * 3 + 2] = c4.z;
    }
    cx = c4.x; cy = c4.y; cz = c4.z;
  }
}

extern "C" void kernel_launch(void* const* d_in, const int* in_sizes, int n_in,
                              void* d_out, int out_size, void* d_ws, size_t ws_size,
                              hipStream_t stream) {
  (void)in_sizes; (void)n_in; (void)out_size; (void)ws_size;
  const float* pts = (const float*)d_in[0];
  float* out = (float*)d_out;
  ull* ws = (ull*)d_ws;
  fps_kernel<<<dim3(NB * WPB), dim3(TPB), 0, stream>>>(pts, out, ws);
}